// Round 5
// baseline (261.996 us; speedup 1.0000x reference)
//
#include <hip/hip_runtime.h>

#define Bn 512
#define Cn 202
#define Pn 27
#define Nn 729
#define CHn 200
#define Kn 58
#define OUTCn 64
#define CENTERn 364    // 13*27+13
#define NCHUNK 7
#define POOLR 176      // pool rows incl. zero-pad (slots >= num1 are zero)
#define PSTR 232       // pool row stride in shorts (464 B -> bank stride 20, conflict-free b128)
#define UROW 72        // U row stride in shorts (144 B)
#define ZSLOT 160
#define MCAP 192
#define SPAD 864

// LDS layout (bytes)
#define POOL_BYTES (POOLR * PSTR * 2)      // 81,664
#define U_OFF POOL_BYTES
#define U_BYTES (3 * POOLR * UROW * 2)     // 76,032
#define SLOT_OFF (U_OFF + U_BYTES)         // 157,696
#define LB_BYTES (SLOT_OFF + 1728)         // 159,424  (<= 163,840)
#define TSTR 68                            // transpose row stride (floats)

typedef float f32x4 __attribute__((ext_vector_type(4)));
typedef short s16x8 __attribute__((ext_vector_type(8)));
typedef short s16x4 __attribute__((ext_vector_type(4)));

static __device__ __forceinline__ unsigned short f2bf(float f) {
  unsigned u = __float_as_uint(f);
  u += 0x7fffu + ((u >> 16) & 1u);   // RNE
  return (unsigned short)(u >> 16);
}
static __device__ __forceinline__ float bf2f(short s) {
  return __uint_as_float(((unsigned)(unsigned short)s) << 16);
}

// ---------------- Kernel A: build slot table + masked-pool list per batch ----------------
__global__ __launch_bounds__(256) void src_kernel(const float* __restrict__ x,
                                                  const int* __restrict__ rand_idx,
                                                  short* __restrict__ slotpad_ws,
                                                  short* __restrict__ Mws,
                                                  int* __restrict__ num1_ws) {
  int b = blockIdx.x;
  __shared__ float sp[Nn];
  __shared__ short slotS[Nn];
  __shared__ short M[Nn];
  __shared__ int s_num;
  int tid = threadIdx.x;
  const float* xsp = x + ((size_t)b * Cn + CHn) * Nn;
  for (int n = tid; n < Nn; n += 256) sp[n] = xsp[n];
  __syncthreads();
  float central = sp[CENTERn];
  __syncthreads();
  for (int k = tid; k < Kn; k += 256) sp[rand_idx[b * Kn + k]] = central;
  __syncthreads();
  if (tid == 0) {
    int cm = 0, cz = 0;
    for (int n = 0; n < Nn; ++n) {
      if (sp[n] == central) { M[cm] = (short)n; slotS[n] = (short)cm; cm++; }
      else { slotS[n] = (short)(~cz); cz++; }
    }
    s_num = cm;
  }
  __syncthreads();
  int num = s_num;
  int numc = num < 160 ? num : 160;
  if (tid == 0) num1_ws[b] = numc;
  for (int m = tid; m < MCAP; m += 256) Mws[(size_t)b * MCAP + m] = (m < num) ? M[m] : (short)0;
  for (int idx = tid; idx < 841; idx += 256) {
    int pi = idx / 29, pj = idx - pi * 29;
    short v = (short)ZSLOT;
    if (pi >= 1 && pi <= 27 && pj >= 1 && pj <= 27) {
      int n = (pi - 1) * Pn + (pj - 1);
      int s0 = slotS[n];
      int sv = (s0 >= 0) ? s0 : ((~s0) % num);
      if (sv > 159) sv = 159;
      v = (short)sv;
    }
    slotpad_ws[(size_t)b * SPAD + idx] = v;
  }
}

// ---------------- Kernel B: weights -> bf16, chunked layout Wt2[ck][r][o][32] ----------------
__global__ __launch_bounds__(256) void wprep_kernel(const float* __restrict__ W,
                                                    short* __restrict__ Wt2) {
  int idx = blockIdx.x * 256 + threadIdx.x;
  if (idx >= NCHUNK * 9 * OUTCn * 32) return;
  int ck = idx / (9 * OUTCn * 32);
  int rem = idx - ck * (9 * OUTCn * 32);
  int r = rem / (OUTCn * 32);
  int rem2 = rem - r * (OUTCn * 32);
  int o = rem2 >> 5;
  int cl = rem2 & 31;
  int c = ck * 32 + cl;
  float v = (c < CHn) ? W[((size_t)o * CHn + c) * 9 + r] : 0.f;
  Wt2[idx] = (short)f2bf(v);
}

// ---------------- Kernel C: U = W_r x Pool, then gather-accumulate ----------------
// 1 block/batch, 1024 thr = 16 waves. 3 r-groups (dr = group, dc = r_local).
__global__ __launch_bounds__(1024, 4) void conv_kernel(const float* __restrict__ x,
                                                       const short* __restrict__ Wt2,
                                                       const float* __restrict__ bias,
                                                       const short* __restrict__ slotpad_ws,
                                                       const short* __restrict__ Mws,
                                                       const int* __restrict__ num1_ws,
                                                       float* __restrict__ y) {
  __shared__ __align__(16) char LB[LB_BYTES];
  short* Pool = (short*)LB;                 // [176][232]
  short* U = (short*)(LB + U_OFF);          // [3][176][72] bf16
  short* Slot = (short*)(LB + SLOT_OFF);    // [841]
  float* T = (float*)LB;                    // [368][68] overlay for epilogue

  const int b = blockIdx.x;
  const int tid = threadIdx.x;
  const int lane = tid & 63;
  const int wv = tid >> 6;       // 0..15
  const int l16 = lane & 15;
  const int kg = lane >> 4;      // 0..3

  const float* xb = x + (size_t)b * Cn * Nn;
  const int num1 = num1_ws[b];

  if (tid < 841) Slot[tid] = slotpad_ws[(size_t)b * SPAD + tid];
  for (int i = tid; i < POOL_BYTES / 4; i += 1024) ((unsigned int*)Pool)[i] = 0u;

  // per-thread gather geometry: wave owns pixels [46*wv, 46*wv+46); thread: sub=kg, o-quad=l16*4
  const int pbase = wv * 46;
  const int oq = l16 * 4;
  int sb[12];
  unsigned vmask = 0;
#pragma unroll
  for (int it = 0; it < 12; ++it) {
    int pl = 4 * it + kg;
    int p = pbase + pl;
    bool v = (pl < 46) && (p < Nn);
    int pc = v ? p : (Nn - 1);
    int pi = pc / Pn, pj = pc - pi * Pn;
    sb[it] = pi * 29 + pj;
    if (v) vmask |= (1u << it);
  }

  float acc[12][4];
#pragma unroll
  for (int it = 0; it < 12; ++it)
#pragma unroll
    for (int q = 0; q < 4; ++q) acc[it][q] = 0.f;

  __syncthreads();   // pool zeroed

  // ---- one-time pool gather (bf16): rows [0,num1), channels [0,200)
  {
    const short* Mb = Mws + (size_t)b * MCAP;
    for (int i = tid; i < 50 * POOLR; i += 1024) {
      int cq = i / POOLR;
      int m = i - cq * POOLR;
      if (m < num1) {
        int s = Mb[m];
        const float* xs = xb + (size_t)(cq * 4) * Nn + s;
        float v0 = xs[0], v1 = xs[Nn], v2 = xs[2 * Nn], v3 = xs[3 * Nn];
        s16x4 w4 = {(short)f2bf(v0), (short)f2bf(v1), (short)f2bf(v2), (short)f2bf(v3)};
        *(s16x4*)(Pool + m * PSTR + cq * 4) = w4;
      }
    }
  }
  __syncthreads();   // pool ready

  for (int g = 0; g < 3; ++g) {
    // ---- U-GEMM: U[rl][slot][o] = sum_c W[r=3g+rl][o][c] * Pool[slot][c]
    // 132 combos = rl(3) x ot(4) x nt(11), strided over 16 waves
    for (int c = wv; c < 132; c += 16) {
      int rl = c / 44;
      int rem = c - rl * 44;
      int ot = rem / 11;
      int nt = rem - ot * 11;
      int r = g * 3 + rl;
      const short* wp = Wt2 + ((size_t)r * 64 + ot * 16 + l16) * 32 + kg * 8;
      const short* pp = Pool + (nt * 16 + l16) * PSTR + kg * 8;
      f32x4 a = (f32x4){0.f, 0.f, 0.f, 0.f};
#pragma unroll
      for (int ck = 0; ck < NCHUNK; ++ck) {
        s16x8 av = *(const s16x8*)(wp + ck * (9 * 64 * 32));
        s16x8 bv = *(const s16x8*)(pp + ck * 32);
        a = __builtin_amdgcn_mfma_f32_16x16x32_bf16(av, bv, a, 0, 0, 0);
      }
      // D: col(slot)=l16, row(o)=kg*4+q
      s16x4 u4 = {(short)f2bf(a[0]), (short)f2bf(a[1]), (short)f2bf(a[2]), (short)f2bf(a[3])};
      *(s16x4*)(U + ((size_t)rl * POOLR + nt * 16 + l16) * UROW + ot * 16 + kg * 4) = u4;
    }
    __syncthreads();   // U ready

    // ---- gather-accumulate: acc[n][o] += U[dc][slot(n; dr=g, dc)][o]
#pragma unroll
    for (int it = 0; it < 12; ++it) {
#pragma unroll
      for (int rl = 0; rl < 3; ++rl) {
        int slot = Slot[sb[it] + g * 29 + rl];
        s16x4 u4 = *(const s16x4*)(U + ((size_t)rl * POOLR + slot) * UROW + oq);
        acc[it][0] += bf2f(u4[0]);
        acc[it][1] += bf2f(u4[1]);
        acc[it][2] += bf2f(u4[2]);
        acc[it][3] += bf2f(u4[3]);
      }
    }
    __syncthreads();   // gather done before next group's U overwrite (and epilogue overlay)
  }

  // ---- epilogue: LDS transpose in 2 chunks, coalesced stores ----
  // chunk A: pixels [0, 368) owned by waves 0..7
  if (wv < 8) {
#pragma unroll
    for (int it = 0; it < 12; ++it) {
      if ((vmask >> it) & 1u) {
        int p = pbase + 4 * it + kg;
        *(f32x4*)&T[p * TSTR + oq] = *(f32x4*)&acc[it][0];
      }
    }
  }
  __syncthreads();
#pragma unroll
  for (int q = 0; q < 4; ++q) {
    int o = wv * 4 + q;
    float bo = bias[o];
    float* yo = y + ((size_t)b * OUTCn + o) * Nn;
    for (int ng = 0; ng < 6; ++ng) {
      int n = ng * 64 + lane;
      if (n < 368) yo[n] = T[n * TSTR + o] + bo;
    }
  }
  __syncthreads();
  // chunk B: pixels [368, 729) owned by waves 8..15
  if (wv >= 8) {
#pragma unroll
    for (int it = 0; it < 12; ++it) {
      if ((vmask >> it) & 1u) {
        int p = pbase + 4 * it + kg;
        *(f32x4*)&T[(p - 368) * TSTR + oq] = *(f32x4*)&acc[it][0];
      }
    }
  }
  __syncthreads();
#pragma unroll
  for (int q = 0; q < 4; ++q) {
    int o = wv * 4 + q;
    float bo = bias[o];
    float* yo = y + ((size_t)b * OUTCn + o) * Nn + 368;
    for (int ng = 0; ng < 6; ++ng) {
      int n = ng * 64 + lane;
      if (n < Nn - 368) yo[n] = T[n * TSTR + o] + bo;
    }
  }
}

extern "C" void kernel_launch(void* const* d_in, const int* in_sizes, int n_in,
                              void* d_out, int out_size, void* d_ws, size_t ws_size,
                              hipStream_t stream) {
  const float* x = (const float*)d_in[0];
  const float* W = (const float*)d_in[1];
  const float* bias = (const float*)d_in[2];
  const int* rand_idx = (const int*)d_in[3];
  float* y = (float*)d_out;

  short* slotpad = (short*)d_ws;                                  // 884,736 B
  short* Mws = (short*)((char*)d_ws + 884736);                    // 196,608 B
  int* num1 = (int*)((char*)d_ws + 884736 + 196608);              // 2,048 B
  short* Wt2 = (short*)((char*)d_ws + 884736 + 196608 + 2048);    // 258,048 B

  src_kernel<<<Bn, 256, 0, stream>>>(x, rand_idx, slotpad, Mws, num1);
  wprep_kernel<<<(NCHUNK * 9 * OUTCn * 32 + 255) / 256, 256, 0, stream>>>(W, Wt2);
  conv_kernel<<<Bn, 1024, 0, stream>>>(x, Wt2, bias, slotpad, Mws, num1, y);
}